// Round 3
// baseline (572.926 us; speedup 1.0000x reference)
//
#include <hip/hip_runtime.h>
#include <math.h>

// N=16384 circular. One block = half a row (8192 outputs), 256 threads,
// 32 outputs/thread via register-streaming of the whole fused pipeline.
#define NN 16384
#define TILE 8192
#define RPT 32
#define STEPS 52          // RPT + total receptive-field halo (20)

// LDS layout: pad 1 float per 32 so per-lane stride-32 reads spread banks.
// Position p (local, in [-12, TILE+10)) lives at lidx(p + 12).
__device__ __forceinline__ int lidx(int off) { return off + (off >> 5); }

__device__ __forceinline__ float elu_f(float v) {
    return v > 0.0f ? v : (__expf(v) - 1.0f);
}

__global__ __launch_bounds__(256)
void smag_stream(const float* __restrict__ x,
                 const float* __restrict__ dw,
                 const float* __restrict__ fw,
                 const float* __restrict__ W1, const float* __restrict__ b1,
                 const float* __restrict__ W2, const float* __restrict__ b2,
                 const float* __restrict__ W3, const float* __restrict__ b3,
                 float* __restrict__ out)
{
    const int half = blockIdx.x & 1;
    const int row  = blockIdx.x >> 1;
    const int tb   = half * TILE;
    const float* __restrict__ xr = x   + (size_t)row * NN;
    float* __restrict__ outr     = out + (size_t)row * NN;
    const int tid = threadIdx.x;

    __shared__ float sx[8470];   // lidx(8213)=8469

    // ---- stage x tile [tb-10, tb+TILE+10) into LDS (coalesced) ----
    #pragma unroll
    for (int k = 0; k < 8; ++k) {
        const int i = (k * 256 + tid) * 4;            // [0, 8192)
        const float4 v = *reinterpret_cast<const float4*>(xr + tb + i);
        const int d = lidx(i + 12);                   // never straddles a pad
        sx[d] = v.x; sx[d+1] = v.y; sx[d+2] = v.z; sx[d+3] = v.w;
    }
    if (tid < 20) {
        const int qq = (tid < 10) ? (tid - 10) : (TILE + tid - 10);
        const int g  = (tb + qq + NN) & (NN - 1);
        sx[lidx(qq + 12)] = xr[g];
    }

    // ---- hoist small weights ----
    const float d0 = dw[0], d1 = dw[1], d2 = dw[2], d3 = dw[3], d4 = dw[4];
    const float g0 = fw[0], g1 = fw[1], g2 = fw[2];
    const float B3 = b3[0];
    const float CUTOFF = 2.0f / 16384.0f;
    const float SQRT2  = 1.41421356237309515f;

    __syncthreads();

    // ---- register-streaming pipeline ----
    const int b33 = tid * 33;     // lidx(tid*32 + c) = tid*33 + c + (c>>5) for c<64
    float xw[5] = {0,0,0,0,0};
    float xd[7] = {0,0,0,0,0,0,0};
    float f1[5] = {0,0,0,0,0};
    float h1[6][5] = {};
    float h2[3][5] = {};
    float yy[5] = {0,0,0,0,0};
    float ob[RPT];

    #pragma unroll
    for (int s = 0; s < STEPS; ++s) {
        // new x sample at local position q = tid*32 - 10 + s
        // LDS offset = q + 12 = tid*32 + (s + 2)  ->  b33 + (s+2) + ((s+2)>>5)
        xw[4] = xw[3]; xw[3] = xw[2]; xw[2] = xw[1]; xw[1] = xw[0];
        xw[0] = sx[b33 + (s + 2) + ((s + 2) >> 5)];

        if (s >= 4) {
            // xdiff & feat1 at p1 = q-2 ; xw[4..0] = x[p1-2..p1+2]
            #pragma unroll
            for (int k = 6; k > 0; --k) xd[k] = xd[k-1];
            #pragma unroll
            for (int k = 4; k > 0; --k) f1[k] = f1[k-1];
            xd[0] = d0*xw[4] + d1*xw[3] + d2*xw[2] + d3*xw[1] + d4*xw[0];
            f1[0] = xw[2] - (g0*xw[3] + g1*xw[2] + g2*xw[1]);
        }
        if (s >= 8) {
            // h1 at p2 = p1-2 ; inputs xd[4-k], f1[4-k] = feat[p2-2+k]
            #pragma unroll
            for (int c = 0; c < 6; ++c) {
                #pragma unroll
                for (int k = 4; k > 0; --k) h1[c][k] = h1[c][k-1];
            }
            #pragma unroll
            for (int c = 0; c < 6; ++c) {
                float a = b1[c];
                #pragma unroll
                for (int k = 0; k < 5; ++k)
                    a += W1[c*10 + k] * xd[4-k] + W1[c*10 + 5 + k] * f1[4-k];
                h1[c][0] = elu_f(a);
            }
        }
        if (s >= 12) {
            // h2 at p3 = p2-2
            #pragma unroll
            for (int c = 0; c < 3; ++c) {
                #pragma unroll
                for (int k = 4; k > 0; --k) h2[c][k] = h2[c][k-1];
            }
            #pragma unroll
            for (int c = 0; c < 3; ++c) {
                float a = b2[c];
                #pragma unroll
                for (int ci = 0; ci < 6; ++ci)
                    #pragma unroll
                    for (int k = 0; k < 5; ++k)
                        a += W2[c*30 + ci*5 + k] * h1[ci][4-k];
                h2[c][0] = elu_f(a);
            }
        }
        if (s >= 16) {
            // y at p4 = p3-2 ; xdiff at p4 is xd[6]
            #pragma unroll
            for (int k = 4; k > 0; --k) yy[k] = yy[k-1];
            float a = B3;
            #pragma unroll
            for (int ci = 0; ci < 3; ++ci)
                #pragma unroll
                for (int k = 0; k < 5; ++k)
                    a += W3[ci*5 + k] * h2[ci][4-k];
            float cs = elu_f(a);
            cs = fminf(fmaxf(cs, 0.0f), 1.0f);
            const float t = cs * CUTOFF;
            const float xv = xd[6];
            yy[0] = SQRT2 * t * t * fabsf(xv) * xv;
        }
        if (s >= 20) {
            // out at p5 = p4-2 ; yy[4..0] = y[p5-2..p5+2]
            ob[s - 20] = d0*yy[4] + d1*yy[3] + d2*yy[2] + d3*yy[1] + d4*yy[0];
        }
    }

    // ---- stage outputs through LDS for coalesced stores ----
    __syncthreads();   // all sx reads done before overwrite
    #pragma unroll
    for (int j = 0; j < RPT; ++j)
        sx[b33 + (j + 12) + ((j + 12) >> 5)] = ob[j];
    __syncthreads();

    #pragma unroll
    for (int k = 0; k < 8; ++k) {
        const int i = (k * 256 + tid) * 4;
        const int d = lidx(i + 12);                   // run of 4 never straddles
        const float4 v = make_float4(sx[d], sx[d+1], sx[d+2], sx[d+3]);
        *reinterpret_cast<float4*>(outr + tb + i) = v;
    }
}

extern "C" void kernel_launch(void* const* d_in, const int* in_sizes, int n_in,
                              void* d_out, int out_size, void* d_ws, size_t ws_size,
                              hipStream_t stream) {
    const float* x  = (const float*)d_in[0];
    const float* dw = (const float*)d_in[1];
    const float* fw = (const float*)d_in[2];
    const float* W1 = (const float*)d_in[3];
    const float* b1 = (const float*)d_in[4];
    const float* W2 = (const float*)d_in[5];
    const float* b2 = (const float*)d_in[6];
    const float* W3 = (const float*)d_in[7];
    const float* b3 = (const float*)d_in[8];
    float* out = (float*)d_out;

    const int B = 1024;
    dim3 grid(B * (NN / TILE));   // 2048 blocks
    dim3 block(256);
    hipLaunchKernelGGL(smag_stream, grid, block, 0, stream,
                       x, dw, fw, W1, b1, W2, b2, W3, b3, out);
}

// Round 4
// 125.915 us; speedup vs baseline: 4.5501x; 4.5501x over previous
//
#include <hip/hip_runtime.h>
#include <math.h>

#define NN 16384
#define T 512

typedef float f2 __attribute__((ext_vector_type(2)));

__device__ __forceinline__ f2 elu2(f2 v) {
    f2 e;
    e.x = __expf(v.x);
    e.y = __expf(v.y);
    const f2 zero = (f2)0.0f;
    return __builtin_elementwise_max(v, zero)
         + __builtin_elementwise_min(e - 1.0f, zero);
}

__global__ __launch_bounds__(256, 5)
void smag_pk(const float* __restrict__ x,
             const float* __restrict__ dw,
             const float* __restrict__ fw,
             const float* __restrict__ W1, const float* __restrict__ b1,
             const float* __restrict__ W2, const float* __restrict__ b2,
             const float* __restrict__ W3, const float* __restrict__ b3,
             float* __restrict__ out)
{
    const int blk = blockIdx.x & 31;        // 32 tiles per row
    const int row = blockIdx.x >> 5;
    const int tb  = blk * T;
    const int tid = threadIdx.x;
    const float* __restrict__ xr = x   + (size_t)row * NN;
    float* __restrict__ outr     = out + (size_t)row * NN;

    // One arena, even offsets -> every float2 access is 8B-aligned.
    __shared__ __align__(16) float sm[6812];
    float* const sx  = sm;          // [536]     x    : idx = p + 12, p in [-10,522)
    float* const sxd = sm + 536;    // [528]     xd   : idx = p + 8,  p in [-8,520)
    float* const sf1 = sm + 1064;   // [528]     f1   : idx = p + 8
    float* const sh1 = sm + 1592;   // [6][524]  h1   : idx = c*524 + p + 6, p in [-6,518)
    float* const sh2 = sm + 4736;   // [3][520]  h2   : idx = c*520 + p + 4, p in [-4,516)
    float* const sy  = sm + 6296;   // [516]     y    : idx = p + 2,  p in [-2,514)

    // ---- stage x into LDS (coalesced f2 + tiny circular halo) ----
    {
        f2 v = *(const f2*)(xr + tb + 2 * tid);
        *(f2*)(sx + 2 * tid + 12) = v;
        if (tid < 20) {
            int p = (tid < 10) ? (tid - 10) : (T + tid - 10);
            sx[p + 12] = xr[(tb + p + NN) & (NN - 1)];
        }
    }

    const float d0 = dw[0], d1 = dw[1], d2 = dw[2], d3 = dw[3], d4 = dw[4];
    const float g0 = fw[0], g1 = fw[1], g2 = fw[2];
    __syncthreads();

    // ---- stage 1: xdiff + (x - box) on pairs, p in [-8,520) ----
    auto S1 = [&](int p) {
        f2 L0 = *(f2*)(sx + p + 10);     // x[p-2], x[p-1]
        f2 L1 = *(f2*)(sx + p + 12);     // x[p],   x[p+1]
        f2 L2 = *(f2*)(sx + p + 14);     // x[p+2], x[p+3]
        f2 a12 = {L0.y, L1.x};
        f2 a34 = {L1.y, L2.x};
        f2 xd = L0 * d0 + a12 * d1 + L1 * d2 + a34 * d3 + L2 * d4;
        f2 f1 = L1 - (a12 * g0 + L1 * g1 + a34 * g2);
        *(f2*)(sxd + p + 8) = xd;
        *(f2*)(sf1 + p + 8) = f1;
    };
    S1(2 * tid - 8);
    if (tid < 8) S1(504 + 2 * tid);
    __syncthreads();

    // ---- stage 2: h1 = elu(conv5(feat,W1)+b1), p in [-6,518) ----
    auto S2 = [&](int p) {
        f2 X0 = *(f2*)(sxd + p + 6);
        f2 X1 = *(f2*)(sxd + p + 8);
        f2 X2 = *(f2*)(sxd + p + 10);
        f2 F0 = *(f2*)(sf1 + p + 6);
        f2 F1 = *(f2*)(sf1 + p + 8);
        f2 F2 = *(f2*)(sf1 + p + 10);
        f2 xa[5] = {X0, {X0.y, X1.x}, X1, {X1.y, X2.x}, X2};
        f2 fa[5] = {F0, {F0.y, F1.x}, F1, {F1.y, F2.x}, F2};
        #pragma unroll
        for (int c = 0; c < 6; ++c) {
            f2 a = (f2)b1[c];
            #pragma unroll
            for (int k = 0; k < 5; ++k)
                a = a + xa[k] * W1[c * 10 + k] + fa[k] * W1[c * 10 + 5 + k];
            *(f2*)(sh1 + c * 524 + p + 6) = elu2(a);
        }
    };
    S2(2 * tid - 6);
    if (tid < 6) S2(506 + 2 * tid);
    __syncthreads();

    // ---- stage 3: h2 = elu(conv5(h1,W2)+b2), p in [-4,516) ----
    auto S3 = [&](int p) {
        f2 acc0 = (f2)b2[0], acc1 = (f2)b2[1], acc2 = (f2)b2[2];
        #pragma unroll
        for (int ci = 0; ci < 6; ++ci) {
            const float* hb = sh1 + ci * 524 + p + 4;   // h1[ci] at position p-2
            f2 H0 = *(f2*)(hb);
            f2 H1 = *(f2*)(hb + 2);
            f2 H2 = *(f2*)(hb + 4);
            f2 ha[5] = {H0, {H0.y, H1.x}, H1, {H1.y, H2.x}, H2};
            #pragma unroll
            for (int k = 0; k < 5; ++k) {
                acc0 = acc0 + ha[k] * W2[0 * 30 + ci * 5 + k];
                acc1 = acc1 + ha[k] * W2[1 * 30 + ci * 5 + k];
                acc2 = acc2 + ha[k] * W2[2 * 30 + ci * 5 + k];
            }
        }
        *(f2*)(sh2 + 0 * 520 + p + 4) = elu2(acc0);
        *(f2*)(sh2 + 1 * 520 + p + 4) = elu2(acc1);
        *(f2*)(sh2 + 2 * 520 + p + 4) = elu2(acc2);
    };
    S3(2 * tid - 4);
    if (tid < 4) S3(508 + 2 * tid);
    __syncthreads();

    // ---- stage 4: cs -> y (sqrt2 folded), p in [-2,514) ----
    const float B3v = b3[0];
    auto S4 = [&](int p) {
        f2 a = (f2)B3v;
        #pragma unroll
        for (int ci = 0; ci < 3; ++ci) {
            const float* hb = sh2 + ci * 520 + p + 2;   // h2[ci] at position p-2
            f2 H0 = *(f2*)(hb);
            f2 H1 = *(f2*)(hb + 2);
            f2 H2 = *(f2*)(hb + 4);
            f2 ha1 = {H0.y, H1.x};
            f2 ha3 = {H1.y, H2.x};
            a = a + H0 * W3[ci * 5 + 0] + ha1 * W3[ci * 5 + 1] + H1 * W3[ci * 5 + 2]
                  + ha3 * W3[ci * 5 + 3] + H2 * W3[ci * 5 + 4];
        }
        f2 cs = elu2(a);
        cs = __builtin_elementwise_min(__builtin_elementwise_max(cs, (f2)0.0f), (f2)1.0f);
        f2 xd = *(f2*)(sxd + p + 8);
        f2 t = cs * (float)(2.0 / 16384.0);
        f2 axd = __builtin_elementwise_abs(xd);
        f2 y = (t * t) * (axd * xd) * 1.41421356237309515f;
        *(f2*)(sy + p + 2) = y;
    };
    S4(2 * tid - 2);
    if (tid < 2) S4(510 + 2 * tid);
    __syncthreads();

    // ---- stage 5: out = conv5(y, dw), straight to global (coalesced f2) ----
    {
        const int p = 2 * tid;
        f2 Y0 = *(f2*)(sy + p);          // y[p-2], y[p-1]
        f2 Y1 = *(f2*)(sy + p + 2);      // y[p],   y[p+1]
        f2 Y2 = *(f2*)(sy + p + 4);      // y[p+2], y[p+3]
        f2 a12 = {Y0.y, Y1.x};
        f2 a34 = {Y1.y, Y2.x};
        f2 o = Y0 * d0 + a12 * d1 + Y1 * d2 + a34 * d3 + Y2 * d4;
        *(f2*)(outr + tb + p) = o;
    }
}

extern "C" void kernel_launch(void* const* d_in, const int* in_sizes, int n_in,
                              void* d_out, int out_size, void* d_ws, size_t ws_size,
                              hipStream_t stream) {
    const float* x  = (const float*)d_in[0];
    const float* dw = (const float*)d_in[1];
    const float* fw = (const float*)d_in[2];
    const float* W1 = (const float*)d_in[3];
    const float* b1 = (const float*)d_in[4];
    const float* W2 = (const float*)d_in[5];
    const float* b2 = (const float*)d_in[6];
    const float* W3 = (const float*)d_in[7];
    const float* b3 = (const float*)d_in[8];
    float* out = (float*)d_out;

    const int B = 1024;
    dim3 grid(B * (NN / T));    // 32768 blocks
    dim3 block(256);
    hipLaunchKernelGGL(smag_pk, grid, block, 0, stream,
                       x, dw, fw, W1, b1, W2, b2, W3, b3, out);
}